// Round 12
// baseline (755.574 us; speedup 1.0000x reference)
//
#include <hip/hip_runtime.h>
#include <hip/hip_bf16.h>

#define N_NODES 50000
#define N_EDGES 1200000
#define EPS_BN 1e-5f
#define NB 1024
#define RPB 49      // ceil(50000/1024)
#define CAP 2048    // per-bucket tmp capacity
#define MIDCOL 25000

typedef __attribute__((ext_vector_type(8))) short short8;
typedef __attribute__((ext_vector_type(4))) float f32x4;
typedef __attribute__((ext_vector_type(4))) unsigned int u32x4;

union U16x8 { uint4 u; short8 s; };

__device__ __forceinline__ float lo2f(unsigned int u){ return __uint_as_float(u << 16); }
__device__ __forceinline__ float hi2f(unsigned int u){ return __uint_as_float(u & 0xffff0000u); }
__device__ __forceinline__ float b2f(unsigned short u){ return __uint_as_float(((unsigned int)u) << 16); }
__device__ __forceinline__ unsigned short f2b(float f){
  __hip_bfloat16 b = __float2bfloat16(f);
  return __builtin_bit_cast(unsigned short, b);
}

// ---------------- CSR build: binned, packed records, col-half split ----------------
__global__ void binA(const int* __restrict__ row, const int* __restrict__ col,
                     int* __restrict__ bcnt, int* __restrict__ tmp, int E){
  __shared__ int hist[NB];
  __shared__ int base[NB];
  for (int i=threadIdx.x; i<NB; i+=256) hist[i] = 0;
  __syncthreads();
  int e0 = blockIdx.x*4096;
  int r_[16], c_[16];
  #pragma unroll
  for (int k=0;k<16;k++){
    int e = e0 + k*256 + threadIdx.x;
    if (e < E){
      r_[k] = row[e]; c_[k] = col[e];
      atomicAdd(&hist[r_[k]/RPB], 1);
    } else r_[k] = -1;
  }
  __syncthreads();
  for (int i=threadIdx.x; i<NB; i+=256){
    int cnt = hist[i];
    base[i] = cnt ? atomicAdd(&bcnt[i], cnt) : 0;
    hist[i] = 0;
  }
  __syncthreads();
  #pragma unroll
  for (int k=0;k<16;k++){
    if (r_[k] >= 0){
      int b = r_[k]/RPB;
      int lr = r_[k] - b*RPB;
      int p = base[b] + atomicAdd(&hist[b], 1);
      tmp[(size_t)b*CAP + p] = (lr << 16) | c_[k];   // col < 65536
    }
  }
}

__global__ void scan1024(const int* __restrict__ bcnt, int* __restrict__ bbase,
                         int* __restrict__ offs, int n, int E){
  __shared__ int tmp[NB];
  int i = threadIdx.x;
  int v = bcnt[i];
  tmp[i] = v;
  __syncthreads();
  for (int off=1; off<NB; off<<=1){
    int t = (i >= off) ? tmp[i-off] : 0;
    __syncthreads();
    tmp[i] += t;
    __syncthreads();
  }
  bbase[i] = tmp[i] - v;
  if (i == 0) offs[n] = E;
}

// per-row split: [offs[r], midp[r]) = cols < MIDCOL; [midp[r], offs[r+1]) = rest
__global__ void binB(const int* __restrict__ bcnt, const int* __restrict__ bbase,
                     const int* __restrict__ tmp,
                     int* __restrict__ offs, int* __restrict__ midp,
                     float* __restrict__ dinv, float* __restrict__ rdeg,
                     int* __restrict__ ep, int n){
  __shared__ int cl[RPB], ch[RPB], rl[RPB], rh[RPB];
  int b = blockIdx.x;
  int r0 = b*RPB;
  int m = bcnt[b];
  size_t tbase = (size_t)b*CAP;
  for (int i=threadIdx.x; i<RPB; i+=256){ cl[i]=0; ch[i]=0; }
  __syncthreads();
  for (int t=threadIdx.x; t<m; t+=256){
    int v = tmp[tbase+t];
    if ((v & 0xFFFF) < MIDCOL) atomicAdd(&cl[v>>16], 1);
    else                       atomicAdd(&ch[v>>16], 1);
  }
  __syncthreads();
  if (threadIdx.x == 0){
    int acc = bbase[b];
    #pragma unroll
    for (int i=0;i<RPB;i++){ rl[i] = acc; acc += cl[i]; rh[i] = acc; acc += ch[i]; }
  }
  __syncthreads();
  if (threadIdx.x < RPB){
    int r = r0 + threadIdx.x;
    if (r < n){
      offs[r] = rl[threadIdx.x];
      midp[r] = rh[threadIdx.x];
      int d = cl[threadIdx.x] + ch[threadIdx.x];
      dinv[r] = (d>0) ? rsqrtf((float)d) : 0.f;
      rdeg[r] = (d>0) ? sqrtf((float)d) : 0.f;
    }
  }
  __syncthreads();
  for (int i=threadIdx.x; i<RPB; i+=256){ cl[i]=0; ch[i]=0; }
  __syncthreads();
  for (int t=threadIdx.x; t<m; t+=256){
    int v = tmp[tbase+t];
    int lr = v >> 16, c = v & 0xFFFF;
    int p;
    if (c < MIDCOL) p = rl[lr] + atomicAdd(&cl[lr], 1);
    else            p = rh[lr] + atomicAdd(&ch[lr], 1);
    ep[p] = c;
  }
}

// ---- weights: AT (layer1 A=W0-W2) hi/lo at [0,8192); layers2-10 folded at 8192+L*12288;
//      BCT (layer1 [W1 | 2W2], [128 cols][128 k]) single bf16 ----
__global__ void transpose_w(const float* __restrict__ W1, const float* __restrict__ Wr,
                            unsigned short* __restrict__ WTh,
                            unsigned short* __restrict__ WTl,
                            unsigned short* __restrict__ BCT){
  int t = blockIdx.x*256 + threadIdx.x;
  if (t < 8192){
    int c = t/128, k = t%128;
    float val = W1[(size_t)k*64 + c] - W1[(size_t)(256+k)*64 + c];
    unsigned short h = f2b(val);
    WTh[t] = h; WTl[t] = f2b(val - b2f(h));
  } else if (t < 118784){
    int u = t - 8192;
    int L = u/12288, r2 = u%12288;
    int c = r2/192, kk = r2%192;
    int seg = kk/64, f = kk%64;
    const float* WL = Wr + (size_t)L*12288;
    float val;
    if (seg==0)      val = WL[(size_t)f*64 + c] - WL[(size_t)(128+f)*64 + c];
    else if (seg==1) val = WL[(size_t)(64+f)*64 + c];
    else             val = 2.f * WL[(size_t)(128+f)*64 + c];
    unsigned short h = f2b(val);
    WTh[t] = h; WTl[t] = f2b(val - b2f(h));
  } else if (t < 135168){
    int u = t - 118784;
    int j = u/128, k = u%128;
    float val = (j < 64) ? W1[(size_t)(128+k)*64 + j]
                         : 2.f * W1[(size_t)(256+k)*64 + (j-64)];
    BCT[u] = f2b(val);
  }
}

// ---------------- SpMM, column-phased ----------------
__device__ __forceinline__ void spmm_acc8(uint4 u, float* a){
  a[0] += lo2f(u.x);
  a[1] += hi2f(u.x);
  a[2] += lo2f(u.y);
  a[3] += hi2f(u.y);
  a[4] += lo2f(u.z);
  a[5] += hi2f(u.z);
  a[6] += lo2f(u.w);
  a[7] += hi2f(u.w);
}

// Phase A: gather cols < MIDCOL (3.2MB working set, L2-resident), fp32 partial (nt store)
__global__ void spmmA(const int* __restrict__ offs, const int* __restrict__ midp,
                      const int* __restrict__ ep,
                      const unsigned short* __restrict__ src,
                      float* __restrict__ part, int n){
  int lane = threadIdx.x & 63;
  int wv = threadIdx.x >> 6;
  int lr = lane >> 3;
  int li = lane & 7;
  int row = (blockIdx.x*4 + wv)*8 + lr;
  int s = 0, e = 0;
  if (row < n){ s = offs[row]; e = midp[row]; }
  float a[8];
  #pragma unroll
  for (int c=0;c<8;c++) a[c]=0.f;
  const int fb = li*8;
  int j = s;
  for (; j+4 <= e; j += 4){
    int c0 = ep[j+0];
    int c1 = ep[j+1];
    int c2 = ep[j+2];
    int c3 = ep[j+3];
    uint4 u0 = *(const uint4*)(src + (size_t)c0*64 + fb);
    uint4 u1 = *(const uint4*)(src + (size_t)c1*64 + fb);
    uint4 u2 = *(const uint4*)(src + (size_t)c2*64 + fb);
    uint4 u3 = *(const uint4*)(src + (size_t)c3*64 + fb);
    spmm_acc8(u0, a);
    spmm_acc8(u1, a);
    spmm_acc8(u2, a);
    spmm_acc8(u3, a);
  }
  for (; j < e; ++j){
    uint4 u = *(const uint4*)(src + (size_t)ep[j]*64 + fb);
    spmm_acc8(u, a);
  }
  if (row < n){
    f32x4 v0 = {a[0], a[1], a[2], a[3]};
    f32x4 v1 = {a[4], a[5], a[6], a[7]};
    f32x4* pp = (f32x4*)(part + (size_t)row*64 + fb);
    __builtin_nontemporal_store(v0, pp);
    __builtin_nontemporal_store(v1, pp+1);
  }
}

// Phase B: gather cols >= MIDCOL, add partial, scale per MODE, bf16 out (nt store)
// MODE 0: -dv*a; 1: -dv^2*a; 2: dv*(padd + -dv*a)
template<int MODE>
__global__ void spmmB(const int* __restrict__ offs, const int* __restrict__ midp,
                      const int* __restrict__ ep,
                      const float* __restrict__ dinv,
                      const unsigned short* __restrict__ src,
                      const float* __restrict__ part,
                      const unsigned short* __restrict__ padd,
                      unsigned short* __restrict__ dst, int n){
  int lane = threadIdx.x & 63;
  int wv = threadIdx.x >> 6;
  int lr = lane >> 3;
  int li = lane & 7;
  int row = (blockIdx.x*4 + wv)*8 + lr;
  int s = 0, e = 0;
  if (row < n){ s = midp[row]; e = offs[row+1]; }
  float a[8];
  #pragma unroll
  for (int c=0;c<8;c++) a[c]=0.f;
  const int fb = li*8;
  int j = s;
  for (; j+4 <= e; j += 4){
    int c0 = ep[j+0];
    int c1 = ep[j+1];
    int c2 = ep[j+2];
    int c3 = ep[j+3];
    uint4 u0 = *(const uint4*)(src + (size_t)c0*64 + fb);
    uint4 u1 = *(const uint4*)(src + (size_t)c1*64 + fb);
    uint4 u2 = *(const uint4*)(src + (size_t)c2*64 + fb);
    uint4 u3 = *(const uint4*)(src + (size_t)c3*64 + fb);
    spmm_acc8(u0, a);
    spmm_acc8(u1, a);
    spmm_acc8(u2, a);
    spmm_acc8(u3, a);
  }
  for (; j < e; ++j){
    uint4 u = *(const uint4*)(src + (size_t)ep[j]*64 + fb);
    spmm_acc8(u, a);
  }
  if (row < n){
    const f32x4* pp = (const f32x4*)(part + (size_t)row*64 + fb);
    f32x4 p0 = __builtin_nontemporal_load(pp);
    f32x4 p1 = __builtin_nontemporal_load(pp+1);
    a[0]+=p0.x; a[1]+=p0.y; a[2]+=p0.z; a[3]+=p0.w;
    a[4]+=p1.x; a[5]+=p1.y; a[6]+=p1.z; a[7]+=p1.w;
    float dv = dinv[row];
    float uv[8];
    #pragma unroll
    for (int c=0;c<8;c++) uv[c] = -dv * a[c];
    if (MODE == 2){
      uint4 pu = *(const uint4*)(padd + (size_t)row*64 + fb);
      float pv[8] = {lo2f(pu.x),hi2f(pu.x),lo2f(pu.y),hi2f(pu.y),
                     lo2f(pu.z),hi2f(pu.z),lo2f(pu.w),hi2f(pu.w)};
      #pragma unroll
      for (int c=0;c<8;c++) uv[c] = dv*(pv[c] + uv[c]);
    } else if (MODE == 1){
      #pragma unroll
      for (int c=0;c<8;c++) uv[c] = dv*uv[c];
    }
    u32x4 o;
    o.x = (unsigned int)f2b(uv[0]) | ((unsigned int)f2b(uv[1]) << 16);
    o.y = (unsigned int)f2b(uv[2]) | ((unsigned int)f2b(uv[3]) << 16);
    o.z = (unsigned int)f2b(uv[4]) | ((unsigned int)f2b(uv[5]) << 16);
    o.w = (unsigned int)f2b(uv[6]) | ((unsigned int)f2b(uv[7]) << 16);
    __builtin_nontemporal_store(o, (u32x4*)(dst + (size_t)row*64 + fb));
  }
}

// ---- gemm1 (layer1): [pb | qs] = x(fp32->bf16) @ BCT[128][128]; qs dinv-scaled ----
__global__ void gemm1_l1(const float* __restrict__ x, const unsigned short* __restrict__ BCT,
                         const float* __restrict__ dinv,
                         unsigned short* __restrict__ pb, unsigned short* __restrict__ qs,
                         int n){
  __shared__ unsigned short wlds[128*128];
  #pragma unroll
  for (int c0=0; c0<2048; c0+=256){
    int c = c0 + threadIdx.x;
    int col = c >> 4, k8 = c & 15;
    uint4 v = *(const uint4*)(BCT + (size_t)col*128 + k8*8);
    int byte = (col*128 + k8*8)*2;
    byte ^= (col & 7) << 4;
    *(uint4*)((char*)wlds + byte) = v;
  }
  int lane = threadIdx.x & 63;
  int wv = threadIdx.x >> 6;
  int mrow = lane & 15;
  int kg = lane >> 4;
  int brow = blockIdx.x*64 + wv*16;
  int m = brow + mrow;
  bool mv = m < n;

  U16x8 af[4];
  #pragma unroll
  for (int kk=0;kk<4;kk++){
    int koff = kk*32 + kg*8;
    unsigned int* hp = (unsigned int*)&af[kk].u;
    if (mv){
      const float* gp = x + (size_t)m*128 + koff;
      float4 v0 = *(const float4*)gp;
      float4 v1 = *(const float4*)(gp+4);
      float g[8] = {v0.x,v0.y,v0.z,v0.w,v1.x,v1.y,v1.z,v1.w};
      #pragma unroll
      for (int p=0;p<4;p++)
        hp[p] = (unsigned int)f2b(g[2*p]) | ((unsigned int)f2b(g[2*p+1]) << 16);
    } else {
      af[kk].u = make_uint4(0,0,0,0);
    }
  }
  __syncthreads();

  f32x4 acc[8];
  #pragma unroll
  for (int t=0;t<8;t++) acc[t] = f32x4{0.f,0.f,0.f,0.f};
  #pragma unroll
  for (int kk=0;kk<4;kk++){
    int koff = kk*32 + kg*8;
    #pragma unroll
    for (int t=0;t<8;t++){
      int col = t*16 + mrow;
      int byte = (col*128 + koff)*2;
      byte ^= (col & 7) << 4;
      U16x8 b;
      b.u = *(const uint4*)((const char*)wlds + byte);
      acc[t] = __builtin_amdgcn_mfma_f32_16x16x32_bf16(af[kk].s, b.s, acc[t], 0, 0, 0);
    }
  }

  #pragma unroll
  for (int t=0;t<8;t++){
    int col = t*16 + mrow;
    #pragma unroll
    for (int i=0;i<4;i++){
      int r = brow + kg*4 + i;
      if (r < n){
        if (col < 64) pb[(size_t)r*64 + col] = f2b(acc[t][i]);
        else          qs[(size_t)r*64 + col - 64] = f2b(dinv[r]*acc[t][i]);
      }
    }
  }
}

// ---- gemm2 (layer1): gbuf = relu(x @ AT + su + bias), stats ----
__global__ void gemm2_l1(const float* __restrict__ x,
                         const unsigned short* __restrict__ ATh,
                         const unsigned short* __restrict__ ATl,
                         const unsigned short* __restrict__ su,
                         const float* __restrict__ bias,
                         float* __restrict__ out, float* __restrict__ stats, int n){
  __shared__ unsigned short wlds[2*64*128];
  __shared__ float ssum[64];
  __shared__ float ssq[64];
  if (threadIdx.x < 64){ ssum[threadIdx.x] = 0.f; ssq[threadIdx.x] = 0.f; }
  #pragma unroll
  for (int c0=0; c0<2048; c0+=256){
    int c = c0 + threadIdx.x;
    int plane = c >> 10;
    int r = c & 1023;
    int col = r >> 4, k8 = r & 15;
    const unsigned short* srcp = (plane ? ATl : ATh) + (size_t)col*128 + k8*8;
    uint4 v = *(const uint4*)srcp;
    int byte = ((plane*64 + col)*128 + k8*8)*2;
    byte ^= (col & 7) << 4;
    *(uint4*)((char*)wlds + byte) = v;
  }
  int lane = threadIdx.x & 63;
  int wv = threadIdx.x >> 6;
  int mrow = lane & 15;
  int kg = lane >> 4;
  int brow = blockIdx.x*64 + wv*16;
  int m = brow + mrow;
  bool mv = m < n;

  U16x8 afh[4], afl[4];
  #pragma unroll
  for (int kk=0;kk<4;kk++){
    int koff = kk*32 + kg*8;
    unsigned int* hp = (unsigned int*)&afh[kk].u;
    unsigned int* lp = (unsigned int*)&afl[kk].u;
    if (mv){
      const float* gp = x + (size_t)m*128 + koff;
      float4 v0 = *(const float4*)gp;
      float4 v1 = *(const float4*)(gp+4);
      float g[8] = {v0.x,v0.y,v0.z,v0.w,v1.x,v1.y,v1.z,v1.w};
      #pragma unroll
      for (int p=0;p<4;p++){
        unsigned short h0 = f2b(g[2*p]),  h1 = f2b(g[2*p+1]);
        unsigned short l0 = f2b(g[2*p] - b2f(h0)), l1 = f2b(g[2*p+1] - b2f(h1));
        hp[p] = (unsigned int)h0 | ((unsigned int)h1 << 16);
        lp[p] = (unsigned int)l0 | ((unsigned int)l1 << 16);
      }
    } else {
      afh[kk].u = make_uint4(0,0,0,0);
      afl[kk].u = make_uint4(0,0,0,0);
    }
  }
  __syncthreads();

  f32x4 acc[4];
  #pragma unroll
  for (int t=0;t<4;t++) acc[t] = f32x4{0.f,0.f,0.f,0.f};
  #pragma unroll
  for (int kk=0;kk<4;kk++){
    int koff = kk*32 + kg*8;
    #pragma unroll
    for (int t=0;t<4;t++){
      int col = t*16 + mrow;
      int byteh = (col*128 + koff)*2;          byteh ^= (col & 7) << 4;
      int bytel = ((64 + col)*128 + koff)*2;   bytel ^= (col & 7) << 4;
      U16x8 bh, bl;
      bh.u = *(const uint4*)((const char*)wlds + byteh);
      bl.u = *(const uint4*)((const char*)wlds + bytel);
      acc[t] = __builtin_amdgcn_mfma_f32_16x16x32_bf16(afh[kk].s, bh.s, acc[t], 0, 0, 0);
      acc[t] = __builtin_amdgcn_mfma_f32_16x16x32_bf16(afh[kk].s, bl.s, acc[t], 0, 0, 0);
      acc[t] = __builtin_amdgcn_mfma_f32_16x16x32_bf16(afl[kk].s, bh.s, acc[t], 0, 0, 0);
    }
  }

  #pragma unroll
  for (int t=0;t<4;t++){
    int col = t*16 + mrow;
    float bsv = bias[col];
    float s = 0.f, sq = 0.f;
    #pragma unroll
    for (int i=0;i<4;i++){
      int r = brow + kg*4 + i;
      if (r < n){
        float v = acc[t][i] + b2f(su[(size_t)r*64 + col]) + bsv;
        v = fmaxf(v, 0.f);
        out[(size_t)r*64 + col] = v;
        s += v; sq += v*v;
      }
    }
    s  += __shfl_xor(s, 16);  sq += __shfl_xor(sq, 16);
    s  += __shfl_xor(s, 32);  sq += __shfl_xor(sq, 32);
    if (kg == 0){
      atomicAdd(&ssum[col], s);
      atomicAdd(&ssq[col], sq);
    }
  }
  __syncthreads();
  if (threadIdx.x < 64){
    float* sl = stats + (blockIdx.x & 15)*128;
    atomicAdd(&sl[threadIdx.x], ssum[threadIdx.x]);
    atomicAdd(&sl[64+threadIdx.x], ssq[threadIdx.x]);
  }
}

// ---- layers 2-10 GEMM: A0=gbuf+affine (hi/lo), A1=T1s*rdeg, A2=Uu; W hi/lo in LDS ----
__global__ void gemm_mfma64(const float* __restrict__ A0f,
                            const float* __restrict__ scsh,
                            const unsigned short* __restrict__ A1,
                            const unsigned short* __restrict__ A2,
                            const float* __restrict__ rdeg,
                            const unsigned short* __restrict__ WTh,
                            const unsigned short* __restrict__ WTl,
                            const float* __restrict__ bias,
                            float* __restrict__ out,
                            float* __restrict__ stats, int n){
  constexpr int SEGF = 64;
  constexpr int K = 192;
  __shared__ unsigned short wlds[2*64*SEGF];
  __shared__ float ssum[64];
  __shared__ float ssq[64];
  __shared__ float sc_l[64];
  __shared__ float sh_l[64];
  if (threadIdx.x < 64){
    ssum[threadIdx.x] = 0.f; ssq[threadIdx.x] = 0.f;
    sc_l[threadIdx.x] = scsh[threadIdx.x];
    sh_l[threadIdx.x] = scsh[64 + threadIdx.x];
  }

  int lane = threadIdx.x & 63;
  int wv = threadIdx.x >> 6;
  int mrow = lane & 15;
  int kg = lane >> 4;
  int brow = blockIdx.x*64 + wv*16;
  int m = brow + mrow;
  bool mv = m < n;
  float rm = mv ? rdeg[m] : 0.f;

  f32x4 acc[4];
  #pragma unroll
  for (int t=0;t<4;t++) acc[t] = f32x4{0.f,0.f,0.f,0.f};

  #pragma unroll
  for (int seg=0; seg<3; ++seg){
    #pragma unroll
    for (int c0=0; c0<1024; c0+=256){
      int c = c0 + threadIdx.x;
      int plane = c >> 9;
      int r = c & 511;
      int col = r >> 3, k8 = r & 7;
      const unsigned short* srcp = (plane ? WTl : WTh) + (size_t)col*K + seg*SEGF + k8*8;
      uint4 v = *(const uint4*)srcp;
      int byte = ((plane*64 + col)*SEGF + k8*8)*2;
      byte ^= (col & 7) << 4;
      *(uint4*)((char*)wlds + byte) = v;
    }
    U16x8 afh[2], afl[2];
    #pragma unroll
    for (int kk=0; kk<2; ++kk){
      int koff = kk*32 + kg*8;
      if (seg==0){
        float y[8];
        if (mv){
          const float* gp = A0f + (size_t)m*SEGF + koff;
          float4 v0 = *(const float4*)gp;
          float4 v1 = *(const float4*)(gp+4);
          float g[8] = {v0.x,v0.y,v0.z,v0.w,v1.x,v1.y,v1.z,v1.w};
          #pragma unroll
          for (int i=0;i<8;i++){
            int f = koff + i;
            y[i] = fmaf(g[i], sc_l[f], sh_l[f]);
          }
        } else {
          #pragma unroll
          for (int i=0;i<8;i++) y[i] = 0.f;
        }
        unsigned int* hp = (unsigned int*)&afh[kk].u;
        unsigned int* lp = (unsigned int*)&afl[kk].u;
        #pragma unroll
        for (int p=0;p<4;p++){
          unsigned short h0 = f2b(y[2*p]),  h1 = f2b(y[2*p+1]);
          unsigned short l0 = f2b(y[2*p] - b2f(h0)), l1 = f2b(y[2*p+1] - b2f(h1));
          hp[p] = (unsigned int)h0 | ((unsigned int)h1 << 16);
          lp[p] = (unsigned int)l0 | ((unsigned int)l1 << 16);
        }
      } else if (seg==1){
        unsigned int* hp = (unsigned int*)&afh[kk].u;
        if (mv){
          uint4 u = *(const uint4*)(A1 + (size_t)m*SEGF + koff);
          float g[8] = {lo2f(u.x),hi2f(u.x),lo2f(u.y),hi2f(u.y),
                        lo2f(u.z),hi2f(u.z),lo2f(u.w),hi2f(u.w)};
          #pragma unroll
          for (int p=0;p<4;p++)
            hp[p] = (unsigned int)f2b(rm*g[2*p]) | ((unsigned int)f2b(rm*g[2*p+1]) << 16);
        } else afh[kk].u = make_uint4(0,0,0,0);
      } else {
        if (mv) afh[kk].u = *(const uint4*)(A2 + (size_t)m*SEGF + koff);
        else    afh[kk].u = make_uint4(0,0,0,0);
      }
    }
    __syncthreads();
    #pragma unroll
    for (int kk=0; kk<2; ++kk){
      #pragma unroll
      for (int t=0;t<4;t++){
        int col = t*16 + mrow;
        int koff = kk*32 + kg*8;
        int byteh = (col*SEGF + koff)*2;          byteh ^= (col & 7) << 4;
        int bytel = ((64 + col)*SEGF + koff)*2;   bytel ^= (col & 7) << 4;
        U16x8 bh, bl;
        bh.u = *(const uint4*)((const char*)wlds + byteh);
        bl.u = *(const uint4*)((const char*)wlds + bytel);
        acc[t] = __builtin_amdgcn_mfma_f32_16x16x32_bf16(afh[kk].s, bh.s, acc[t], 0, 0, 0);
        acc[t] = __builtin_amdgcn_mfma_f32_16x16x32_bf16(afh[kk].s, bl.s, acc[t], 0, 0, 0);
        if (seg==0)
          acc[t] = __builtin_amdgcn_mfma_f32_16x16x32_bf16(afl[kk].s, bh.s, acc[t], 0, 0, 0);
      }
    }
    __syncthreads();
  }

  #pragma unroll
  for (int t=0;t<4;t++){
    int col = t*16 + mrow;
    float bsv = bias[col];
    float s = 0.f, sq = 0.f;
    #pragma unroll
    for (int i=0;i<4;i++){
      int r = brow + kg*4 + i;
      if (r < n){
        float v = fmaxf(acc[t][i] + bsv, 0.f);
        out[(size_t)r*64 + col] = v;
        s += v; sq += v*v;
      }
    }
    s  += __shfl_xor(s, 16);  sq += __shfl_xor(sq, 16);
    s  += __shfl_xor(s, 32);  sq += __shfl_xor(sq, 32);
    if (kg == 0){
      atomicAdd(&ssum[col], s);
      atomicAdd(&ssq[col], sq);
    }
  }
  __syncthreads();
  if (threadIdx.x < 64){
    float* sl = stats + (blockIdx.x & 15)*128;
    atomicAdd(&sl[threadIdx.x], ssum[threadIdx.x]);
    atomicAdd(&sl[64+threadIdx.x], ssq[threadIdx.x]);
  }
}

// ---- BN-scale: reduce stats -> sc/sh; hs = dinv[node]*(sc*g+sh) bf16 ----
__global__ void bn_scale(const float* __restrict__ g_in, const float* __restrict__ dinv,
                         unsigned short* __restrict__ hs,
                         const float* __restrict__ stats, float* __restrict__ scsh,
                         const float* __restrict__ gamma, const float* __restrict__ beta,
                         int n){
  __shared__ float red[128];
  __shared__ float sc[64], sh[64];
  int tid = threadIdx.x;
  if (tid < 128){
    float s = 0.f;
    #pragma unroll
    for (int r=0;r<16;r++) s += stats[r*128 + tid];
    red[tid] = s;
  }
  __syncthreads();
  if (tid < 64){
    float inv_n = 1.f/(float)n;
    float mu = red[tid]*inv_n;
    float var = red[64+tid]*inv_n - mu*mu;
    float a = gamma[tid]*rsqrtf(var + EPS_BN);
    sc[tid] = a;
    sh[tid] = beta[tid] - mu*a;
    if (blockIdx.x == 0){
      scsh[tid] = a;
      scsh[64+tid] = sh[tid];
    }
  }
  __syncthreads();
  int t = blockIdx.x*256 + tid;
  if (t >= n*8) return;
  int fb = (t & 7)*8;
  int node = t >> 3;
  float dv = dinv[node];
  const float* gp = g_in + (size_t)node*64 + fb;
  float4 v0 = *(const float4*)gp;
  float4 v1 = *(const float4*)(gp + 4);
  float vv[8] = {v0.x, v0.y, v0.z, v0.w, v1.x, v1.y, v1.z, v1.w};
  uint4 o;
  unsigned int* op = (unsigned int*)&o;
  #pragma unroll
  for (int p=0;p<4;p++){
    int f0 = fb + 2*p, f1 = f0 + 1;
    float y0 = dv * fmaf(vv[2*p],   sc[f0], sh[f0]);
    float y1 = dv * fmaf(vv[2*p+1], sc[f1], sh[f1]);
    op[p] = (unsigned int)f2b(y0) | ((unsigned int)f2b(y1) << 16);
  }
  ((uint4*)hs)[t] = o;
}

// ---------------- final: BN(layer10) in fp32 + linear 64->2 ----------------
__global__ void final_linear_bn(const float* __restrict__ g_in,
                                const float* __restrict__ stats,
                                const float* __restrict__ gamma, const float* __restrict__ beta,
                                const float* __restrict__ w, const float* __restrict__ b,
                                float* __restrict__ out, int n){
  __shared__ float red[128];
  __shared__ float sc[64], sh[64];
  int tid = threadIdx.x;
  if (tid < 128){
    float s = 0.f;
    #pragma unroll
    for (int r=0;r<16;r++) s += stats[r*128 + tid];
    red[tid] = s;
  }
  __syncthreads();
  if (tid < 64){
    float inv_n = 1.f/(float)n;
    float mu = red[tid]*inv_n;
    float var = red[64+tid]*inv_n - mu*mu;
    float a = gamma[tid]*rsqrtf(var + EPS_BN);
    sc[tid] = a;
    sh[tid] = beta[tid] - mu*a;
  }
  __syncthreads();
  int i = blockIdx.x*256 + tid;
  if (i >= n) return;
  float a0 = b[0], a1 = b[1];
  const float* gp = g_in + (size_t)i*64;
  #pragma unroll
  for (int k=0;k<64;k++){
    float v = fmaf(gp[k], sc[k], sh[k]);
    a0 = fmaf(v, w[k*2+0], a0);
    a1 = fmaf(v, w[k*2+1], a1);
  }
  out[i*2+0] = a0;
  out[i*2+1] = a1;
}

extern "C" void kernel_launch(void* const* d_in, const int* in_sizes, int n_in,
                              void* d_out, int out_size, void* d_ws, size_t ws_size,
                              hipStream_t stream){
  const float* x     = (const float*)d_in[0];
  const int*   ei    = (const int*)d_in[1];
  const float* W1    = (const float*)d_in[2];
  const float* b1    = (const float*)d_in[3];
  const float* Wr    = (const float*)d_in[4];
  const float* br    = (const float*)d_in[5];
  const float* gamma = (const float*)d_in[6];
  const float* beta  = (const float*)d_in[7];
  const float* lw    = (const float*)d_in[8];
  const float* lb    = (const float*)d_in[9];
  const int N = N_NODES, E = N_EDGES;
  const int* row = ei;
  const int* col = ei + E;

  char* ws = (char*)d_ws;
  size_t off = 0;
  auto alloc = [&](size_t bytes)->void*{
    void* p = ws + off; off = (off + bytes + 255) & ~(size_t)255; return p; };
  float*          dinv  = (float*) alloc((size_t)N*4);
  float*          rdeg  = (float*) alloc((size_t)N*4);
  int*            offs  = (int*)   alloc((size_t)(N+1)*4);
  int*            midp  = (int*)   alloc((size_t)N*4);
  int*            bcnt  = (int*)   alloc(NB*4);
  int*            bbase = (int*)   alloc(NB*4);
  int*            tmp   = (int*)   alloc((size_t)NB*CAP*4);
  int*            ep    = (int*)   alloc((size_t)E*4);
  unsigned short* pb    = (unsigned short*)alloc((size_t)N*64*2);
  unsigned short* qs    = (unsigned short*)alloc((size_t)N*64*2);
  unsigned short* T1s   = (unsigned short*)alloc((size_t)N*64*2);
  unsigned short* Uu    = (unsigned short*)alloc((size_t)N*64*2);
  unsigned short* hs    = (unsigned short*)alloc((size_t)N*64*2);
  float*          part  = (float*) alloc((size_t)N*64*4);
  float*          gbuf  = (float*) alloc((size_t)N*64*4);
  unsigned short* WTh   = (unsigned short*)alloc((size_t)118784*2);
  unsigned short* WTl   = (unsigned short*)alloc((size_t)118784*2);
  unsigned short* BCT   = (unsigned short*)alloc((size_t)16384*2);
  float*          stats = (float*) alloc((size_t)10*2048*4);
  float*          scsh  = (float*) alloc((size_t)10*128*4);

  hipMemsetAsync(bcnt, 0, NB*4, stream);
  hipMemsetAsync(stats, 0, (size_t)10*2048*4, stream);
  binA<<<(E+4095)/4096, 256, 0, stream>>>(row, col, bcnt, tmp, E);
  scan1024<<<1, NB, 0, stream>>>(bcnt, bbase, offs, N, E);
  binB<<<NB, 256, 0, stream>>>(bcnt, bbase, tmp, offs, midp, dinv, rdeg, ep, N);

  transpose_w<<<(135168+255)/256, 256, 0, stream>>>(W1, Wr, WTh, WTl, BCT);

  int sg = (N+31)/32;
  // ---- layer 1 (reassociated; phased spmm) ----
  gemm1_l1<<<(N+63)/64, 256, 0, stream>>>(x, BCT, dinv, pb, qs, N);
  spmmA<<<sg, 256, 0, stream>>>(offs, midp, ep, qs, part, N);
  spmmB<2><<<sg, 256, 0, stream>>>(offs, midp, ep, dinv, qs, part, pb, T1s, N);
  spmmA<<<sg, 256, 0, stream>>>(offs, midp, ep, T1s, part, N);
  spmmB<0><<<sg, 256, 0, stream>>>(offs, midp, ep, dinv, T1s, part, nullptr, Uu, N);
  gemm2_l1<<<(N+63)/64, 256, 0, stream>>>(x, WTh, WTl, Uu, b1, gbuf, stats, N);

  // ---- layers 2..10 ----
  for (int L=0; L<9; ++L){
    bn_scale<<<((N*8)+255)/256, 256, 0, stream>>>(gbuf, dinv, hs,
        stats + (size_t)L*2048, scsh + (size_t)L*128,
        gamma + (size_t)L*64, beta + (size_t)L*64, N);
    spmmA<<<sg, 256, 0, stream>>>(offs, midp, ep, hs, part, N);
    spmmB<1><<<sg, 256, 0, stream>>>(offs, midp, ep, dinv, hs, part, nullptr, T1s, N);
    spmmA<<<sg, 256, 0, stream>>>(offs, midp, ep, T1s, part, N);
    spmmB<0><<<sg, 256, 0, stream>>>(offs, midp, ep, dinv, T1s, part, nullptr, Uu, N);
    gemm_mfma64<<<(N+63)/64, 256, 0, stream>>>(gbuf, scsh + (size_t)L*128, T1s, Uu, rdeg,
        WTh + 8192 + (size_t)L*12288, WTl + 8192 + (size_t)L*12288,
        br + (size_t)L*64, gbuf, stats + (size_t)(L+1)*2048, N);
  }

  final_linear_bn<<<(N+255)/256, 256, 0, stream>>>(gbuf, stats + (size_t)9*2048,
      gamma + (size_t)9*64, beta + (size_t)9*64, lw, lb, (float*)d_out, N);
}

// Round 13
// 631.935 us; speedup vs baseline: 1.1957x; 1.1957x over previous
//
#include <hip/hip_runtime.h>
#include <hip/hip_bf16.h>

#define N_NODES 50000
#define N_EDGES 1200000
#define EPS_BN 1e-5f
#define NB 1024
#define RPB 49    // ceil(50000/1024)
#define CAP 2048  // per-bucket tmp capacity

typedef __attribute__((ext_vector_type(8))) short short8;
typedef __attribute__((ext_vector_type(4))) float f32x4;

union U16x8 { uint4 u; short8 s; };

__device__ __forceinline__ float lo2f(unsigned int u){ return __uint_as_float(u << 16); }
__device__ __forceinline__ float hi2f(unsigned int u){ return __uint_as_float(u & 0xffff0000u); }
__device__ __forceinline__ float b2f(unsigned short u){ return __uint_as_float(((unsigned int)u) << 16); }
__device__ __forceinline__ unsigned short f2b(float f){
  __hip_bfloat16 b = __float2bfloat16(f);
  return __builtin_bit_cast(unsigned short, b);
}

// ---------------- CSR build: binned, packed records ----------------
__global__ void binA(const int* __restrict__ row, const int* __restrict__ col,
                     int* __restrict__ bcnt, int* __restrict__ tmp, int E){
  __shared__ int hist[NB];
  __shared__ int base[NB];
  for (int i=threadIdx.x; i<NB; i+=256) hist[i] = 0;
  __syncthreads();
  int e0 = blockIdx.x*4096;
  int r_[16], c_[16];
  #pragma unroll
  for (int k=0;k<16;k++){
    int e = e0 + k*256 + threadIdx.x;
    if (e < E){
      r_[k] = row[e]; c_[k] = col[e];
      atomicAdd(&hist[r_[k]/RPB], 1);
    } else r_[k] = -1;
  }
  __syncthreads();
  for (int i=threadIdx.x; i<NB; i+=256){
    int cnt = hist[i];
    base[i] = cnt ? atomicAdd(&bcnt[i], cnt) : 0;
    hist[i] = 0;
  }
  __syncthreads();
  #pragma unroll
  for (int k=0;k<16;k++){
    if (r_[k] >= 0){
      int b = r_[k]/RPB;
      int lr = r_[k] - b*RPB;
      int p = base[b] + atomicAdd(&hist[b], 1);
      tmp[(size_t)b*CAP + p] = (lr << 16) | c_[k];   // col < 65536
    }
  }
}

__global__ void scan1024(const int* __restrict__ bcnt, int* __restrict__ bbase,
                         int* __restrict__ offs, int n, int E){
  __shared__ int tmp[NB];
  int i = threadIdx.x;
  int v = bcnt[i];
  tmp[i] = v;
  __syncthreads();
  for (int off=1; off<NB; off<<=1){
    int t = (i >= off) ? tmp[i-off] : 0;
    __syncthreads();
    tmp[i] += t;
    __syncthreads();
  }
  bbase[i] = tmp[i] - v;
  if (i == 0) offs[n] = E;
}

__global__ void binB(const int* __restrict__ bcnt, const int* __restrict__ bbase,
                     const int* __restrict__ tmp,
                     int* __restrict__ offs, float* __restrict__ dinv,
                     float* __restrict__ rdeg, int* __restrict__ ep, int n){
  __shared__ int cnt[RPB];
  __shared__ int roff[RPB];
  int b = blockIdx.x;
  int r0 = b*RPB;
  int m = bcnt[b];
  size_t tbase = (size_t)b*CAP;
  for (int i=threadIdx.x; i<RPB; i+=256) cnt[i] = 0;
  __syncthreads();
  for (int t=threadIdx.x; t<m; t+=256)
    atomicAdd(&cnt[tmp[tbase+t] >> 16], 1);
  __syncthreads();
  if (threadIdx.x == 0){
    int acc = bbase[b];
    #pragma unroll
    for (int i=0;i<RPB;i++){ roff[i] = acc; acc += cnt[i]; }
  }
  __syncthreads();
  if (threadIdx.x < RPB){
    int r = r0 + threadIdx.x;
    if (r < n){
      offs[r] = roff[threadIdx.x];
      int d = cnt[threadIdx.x];
      dinv[r] = (d>0) ? rsqrtf((float)d) : 0.f;
      rdeg[r] = (d>0) ? sqrtf((float)d) : 0.f;
    }
  }
  __syncthreads();
  for (int i=threadIdx.x; i<RPB; i+=256) cnt[i] = 0;
  __syncthreads();
  for (int t=threadIdx.x; t<m; t+=256){
    int v = tmp[tbase+t];
    int lr = v >> 16;
    int p = roff[lr] + atomicAdd(&cnt[lr], 1);
    ep[p] = v & 0xFFFF;
  }
}

// ---- weights: AT (layer1 A=W0-W2) hi/lo at [0,8192); layers2-10 folded at 8192+L*12288;
//      BCT (layer1 [W1 | 2W2], [128 cols][128 k]) single bf16 ----
__global__ void transpose_w(const float* __restrict__ W1, const float* __restrict__ Wr,
                            unsigned short* __restrict__ WTh,
                            unsigned short* __restrict__ WTl,
                            unsigned short* __restrict__ BCT){
  int t = blockIdx.x*256 + threadIdx.x;
  if (t < 8192){
    int c = t/128, k = t%128;
    float val = W1[(size_t)k*64 + c] - W1[(size_t)(256+k)*64 + c];
    unsigned short h = f2b(val);
    WTh[t] = h; WTl[t] = f2b(val - b2f(h));
  } else if (t < 118784){
    int u = t - 8192;
    int L = u/12288, r2 = u%12288;
    int c = r2/192, kk = r2%192;
    int seg = kk/64, f = kk%64;
    const float* WL = Wr + (size_t)L*12288;
    float val;
    if (seg==0)      val = WL[(size_t)f*64 + c] - WL[(size_t)(128+f)*64 + c];
    else if (seg==1) val = WL[(size_t)(64+f)*64 + c];
    else             val = 2.f * WL[(size_t)(128+f)*64 + c];
    unsigned short h = f2b(val);
    WTh[t] = h; WTl[t] = f2b(val - b2f(h));
  } else if (t < 135168){
    int u = t - 118784;
    int j = u/128, k = u%128;
    float val = (j < 64) ? W1[(size_t)(128+k)*64 + j]
                         : 2.f * W1[(size_t)(256+k)*64 + (j-64)];
    BCT[u] = f2b(val);
  }
}

// ---------------- SpMM: MODE 0: -dv*a; 1: -dv^2*a; 2: dv*(padd + -dv*a) ----------------
__device__ __forceinline__ void spmm_acc8(uint4 u, float* a){
  a[0] += lo2f(u.x);
  a[1] += hi2f(u.x);
  a[2] += lo2f(u.y);
  a[3] += hi2f(u.y);
  a[4] += lo2f(u.z);
  a[5] += hi2f(u.z);
  a[6] += lo2f(u.w);
  a[7] += hi2f(u.w);
}

template<int MODE>
__global__ void spmm64(const int* __restrict__ offs, const int* __restrict__ ep,
                       const float* __restrict__ dinv,
                       const unsigned short* __restrict__ src,
                       const unsigned short* __restrict__ padd,
                       unsigned short* __restrict__ dst, int n){
  int lane = threadIdx.x & 63;
  int wv = threadIdx.x >> 6;
  int lr = lane >> 3;
  int li = lane & 7;
  int row = (blockIdx.x*4 + wv)*8 + lr;
  int s = 0, e = 0;
  if (row < n){ s = offs[row]; e = offs[row+1]; }
  float a[8];
  #pragma unroll
  for (int c=0;c<8;c++) a[c]=0.f;
  const int fb = li*8;
  int j = s;
  for (; j+4 <= e; j += 4){
    int c0 = ep[j+0];
    int c1 = ep[j+1];
    int c2 = ep[j+2];
    int c3 = ep[j+3];
    uint4 u0 = *(const uint4*)(src + (size_t)c0*64 + fb);
    uint4 u1 = *(const uint4*)(src + (size_t)c1*64 + fb);
    uint4 u2 = *(const uint4*)(src + (size_t)c2*64 + fb);
    uint4 u3 = *(const uint4*)(src + (size_t)c3*64 + fb);
    spmm_acc8(u0, a);
    spmm_acc8(u1, a);
    spmm_acc8(u2, a);
    spmm_acc8(u3, a);
  }
  for (; j < e; ++j){
    uint4 u = *(const uint4*)(src + (size_t)ep[j]*64 + fb);
    spmm_acc8(u, a);
  }
  if (row < n){
    float dv = dinv[row];
    float uv[8];
    #pragma unroll
    for (int c=0;c<8;c++) uv[c] = -dv * a[c];
    if (MODE == 2){
      uint4 pu = *(const uint4*)(padd + (size_t)row*64 + fb);
      float pv[8] = {lo2f(pu.x),hi2f(pu.x),lo2f(pu.y),hi2f(pu.y),
                     lo2f(pu.z),hi2f(pu.z),lo2f(pu.w),hi2f(pu.w)};
      #pragma unroll
      for (int c=0;c<8;c++) uv[c] = dv*(pv[c] + uv[c]);
    } else if (MODE == 1){
      #pragma unroll
      for (int c=0;c<8;c++) uv[c] = dv*uv[c];
    }
    uint4 o;
    unsigned int* op = (unsigned int*)&o;
    #pragma unroll
    for (int p=0;p<4;p++)
      op[p] = (unsigned int)f2b(uv[2*p]) | ((unsigned int)f2b(uv[2*p+1]) << 16);
    *(uint4*)(dst + (size_t)row*64 + fb) = o;
  }
}

// ---- gemm1 (layer1): [pb | qs] = x(fp32->bf16) @ BCT[128][128]; qs dinv-scaled ----
__global__ void gemm1_l1(const float* __restrict__ x, const unsigned short* __restrict__ BCT,
                         const float* __restrict__ dinv,
                         unsigned short* __restrict__ pb, unsigned short* __restrict__ qs,
                         int n){
  __shared__ unsigned short wlds[128*128];
  #pragma unroll
  for (int c0=0; c0<2048; c0+=256){
    int c = c0 + threadIdx.x;
    int col = c >> 4, k8 = c & 15;
    uint4 v = *(const uint4*)(BCT + (size_t)col*128 + k8*8);
    int byte = (col*128 + k8*8)*2;
    byte ^= (col & 7) << 4;
    *(uint4*)((char*)wlds + byte) = v;
  }
  int lane = threadIdx.x & 63;
  int wv = threadIdx.x >> 6;
  int mrow = lane & 15;
  int kg = lane >> 4;
  int brow = blockIdx.x*64 + wv*16;
  int m = brow + mrow;
  bool mv = m < n;

  U16x8 af[4];
  #pragma unroll
  for (int kk=0;kk<4;kk++){
    int koff = kk*32 + kg*8;
    unsigned int* hp = (unsigned int*)&af[kk].u;
    if (mv){
      const float* gp = x + (size_t)m*128 + koff;
      float4 v0 = *(const float4*)gp;
      float4 v1 = *(const float4*)(gp+4);
      float g[8] = {v0.x,v0.y,v0.z,v0.w,v1.x,v1.y,v1.z,v1.w};
      #pragma unroll
      for (int p=0;p<4;p++)
        hp[p] = (unsigned int)f2b(g[2*p]) | ((unsigned int)f2b(g[2*p+1]) << 16);
    } else {
      af[kk].u = make_uint4(0,0,0,0);
    }
  }
  __syncthreads();

  f32x4 acc[8];
  #pragma unroll
  for (int t=0;t<8;t++) acc[t] = f32x4{0.f,0.f,0.f,0.f};
  #pragma unroll
  for (int kk=0;kk<4;kk++){
    int koff = kk*32 + kg*8;
    #pragma unroll
    for (int t=0;t<8;t++){
      int col = t*16 + mrow;
      int byte = (col*128 + koff)*2;
      byte ^= (col & 7) << 4;
      U16x8 b;
      b.u = *(const uint4*)((const char*)wlds + byte);
      acc[t] = __builtin_amdgcn_mfma_f32_16x16x32_bf16(af[kk].s, b.s, acc[t], 0, 0, 0);
    }
  }

  #pragma unroll
  for (int t=0;t<8;t++){
    int col = t*16 + mrow;
    #pragma unroll
    for (int i=0;i<4;i++){
      int r = brow + kg*4 + i;
      if (r < n){
        if (col < 64) pb[(size_t)r*64 + col] = f2b(acc[t][i]);
        else          qs[(size_t)r*64 + col - 64] = f2b(dinv[r]*acc[t][i]);
      }
    }
  }
}

// ---- gemm2 (layer1): gbuf = relu(x @ AT + su + bias), stats ----
__global__ void gemm2_l1(const float* __restrict__ x,
                         const unsigned short* __restrict__ ATh,
                         const unsigned short* __restrict__ ATl,
                         const unsigned short* __restrict__ su,
                         const float* __restrict__ bias,
                         float* __restrict__ out, float* __restrict__ stats, int n){
  __shared__ unsigned short wlds[2*64*128];
  __shared__ float ssum[64];
  __shared__ float ssq[64];
  if (threadIdx.x < 64){ ssum[threadIdx.x] = 0.f; ssq[threadIdx.x] = 0.f; }
  #pragma unroll
  for (int c0=0; c0<2048; c0+=256){
    int c = c0 + threadIdx.x;
    int plane = c >> 10;
    int r = c & 1023;
    int col = r >> 4, k8 = r & 15;
    const unsigned short* srcp = (plane ? ATl : ATh) + (size_t)col*128 + k8*8;
    uint4 v = *(const uint4*)srcp;
    int byte = ((plane*64 + col)*128 + k8*8)*2;
    byte ^= (col & 7) << 4;
    *(uint4*)((char*)wlds + byte) = v;
  }
  int lane = threadIdx.x & 63;
  int wv = threadIdx.x >> 6;
  int mrow = lane & 15;
  int kg = lane >> 4;
  int brow = blockIdx.x*64 + wv*16;
  int m = brow + mrow;
  bool mv = m < n;

  U16x8 afh[4], afl[4];
  #pragma unroll
  for (int kk=0;kk<4;kk++){
    int koff = kk*32 + kg*8;
    unsigned int* hp = (unsigned int*)&afh[kk].u;
    unsigned int* lp = (unsigned int*)&afl[kk].u;
    if (mv){
      const float* gp = x + (size_t)m*128 + koff;
      float4 v0 = *(const float4*)gp;
      float4 v1 = *(const float4*)(gp+4);
      float g[8] = {v0.x,v0.y,v0.z,v0.w,v1.x,v1.y,v1.z,v1.w};
      #pragma unroll
      for (int p=0;p<4;p++){
        unsigned short h0 = f2b(g[2*p]),  h1 = f2b(g[2*p+1]);
        unsigned short l0 = f2b(g[2*p] - b2f(h0)), l1 = f2b(g[2*p+1] - b2f(h1));
        hp[p] = (unsigned int)h0 | ((unsigned int)h1 << 16);
        lp[p] = (unsigned int)l0 | ((unsigned int)l1 << 16);
      }
    } else {
      afh[kk].u = make_uint4(0,0,0,0);
      afl[kk].u = make_uint4(0,0,0,0);
    }
  }
  __syncthreads();

  f32x4 acc[4];
  #pragma unroll
  for (int t=0;t<4;t++) acc[t] = f32x4{0.f,0.f,0.f,0.f};
  #pragma unroll
  for (int kk=0;kk<4;kk++){
    int koff = kk*32 + kg*8;
    #pragma unroll
    for (int t=0;t<4;t++){
      int col = t*16 + mrow;
      int byteh = (col*128 + koff)*2;          byteh ^= (col & 7) << 4;
      int bytel = ((64 + col)*128 + koff)*2;   bytel ^= (col & 7) << 4;
      U16x8 bh, bl;
      bh.u = *(const uint4*)((const char*)wlds + byteh);
      bl.u = *(const uint4*)((const char*)wlds + bytel);
      acc[t] = __builtin_amdgcn_mfma_f32_16x16x32_bf16(afh[kk].s, bh.s, acc[t], 0, 0, 0);
      acc[t] = __builtin_amdgcn_mfma_f32_16x16x32_bf16(afh[kk].s, bl.s, acc[t], 0, 0, 0);
      acc[t] = __builtin_amdgcn_mfma_f32_16x16x32_bf16(afl[kk].s, bh.s, acc[t], 0, 0, 0);
    }
  }

  #pragma unroll
  for (int t=0;t<4;t++){
    int col = t*16 + mrow;
    float bsv = bias[col];
    float s = 0.f, sq = 0.f;
    #pragma unroll
    for (int i=0;i<4;i++){
      int r = brow + kg*4 + i;
      if (r < n){
        float v = acc[t][i] + b2f(su[(size_t)r*64 + col]) + bsv;
        v = fmaxf(v, 0.f);
        out[(size_t)r*64 + col] = v;
        s += v; sq += v*v;
      }
    }
    s  += __shfl_xor(s, 16);  sq += __shfl_xor(sq, 16);
    s  += __shfl_xor(s, 32);  sq += __shfl_xor(sq, 32);
    if (kg == 0){
      atomicAdd(&ssum[col], s);
      atomicAdd(&ssq[col], sq);
    }
  }
  __syncthreads();
  if (threadIdx.x < 64){
    float* sl = stats + (blockIdx.x & 15)*128;
    atomicAdd(&sl[threadIdx.x], ssum[threadIdx.x]);
    atomicAdd(&sl[64+threadIdx.x], ssq[threadIdx.x]);
  }
}

// ---- layers 2-10 GEMM: A0=gbuf+affine (hi/lo), A1=T1s*rdeg, A2=Uu; W hi/lo in LDS ----
__global__ void gemm_mfma64(const float* __restrict__ A0f,
                            const float* __restrict__ scsh,
                            const unsigned short* __restrict__ A1,
                            const unsigned short* __restrict__ A2,
                            const float* __restrict__ rdeg,
                            const unsigned short* __restrict__ WTh,
                            const unsigned short* __restrict__ WTl,
                            const float* __restrict__ bias,
                            float* __restrict__ out,
                            float* __restrict__ stats, int n){
  constexpr int SEGF = 64;
  constexpr int K = 192;
  __shared__ unsigned short wlds[2*64*SEGF];
  __shared__ float ssum[64];
  __shared__ float ssq[64];
  __shared__ float sc_l[64];
  __shared__ float sh_l[64];
  if (threadIdx.x < 64){
    ssum[threadIdx.x] = 0.f; ssq[threadIdx.x] = 0.f;
    sc_l[threadIdx.x] = scsh[threadIdx.x];
    sh_l[threadIdx.x] = scsh[64 + threadIdx.x];
  }

  int lane = threadIdx.x & 63;
  int wv = threadIdx.x >> 6;
  int mrow = lane & 15;
  int kg = lane >> 4;
  int brow = blockIdx.x*64 + wv*16;
  int m = brow + mrow;
  bool mv = m < n;
  float rm = mv ? rdeg[m] : 0.f;

  f32x4 acc[4];
  #pragma unroll
  for (int t=0;t<4;t++) acc[t] = f32x4{0.f,0.f,0.f,0.f};

  #pragma unroll
  for (int seg=0; seg<3; ++seg){
    #pragma unroll
    for (int c0=0; c0<1024; c0+=256){
      int c = c0 + threadIdx.x;
      int plane = c >> 9;
      int r = c & 511;
      int col = r >> 3, k8 = r & 7;
      const unsigned short* srcp = (plane ? WTl : WTh) + (size_t)col*K + seg*SEGF + k8*8;
      uint4 v = *(const uint4*)srcp;
      int byte = ((plane*64 + col)*SEGF + k8*8)*2;
      byte ^= (col & 7) << 4;
      *(uint4*)((char*)wlds + byte) = v;
    }
    U16x8 afh[2], afl[2];
    #pragma unroll
    for (int kk=0; kk<2; ++kk){
      int koff = kk*32 + kg*8;
      if (seg==0){
        float y[8];
        if (mv){
          const float* gp = A0f + (size_t)m*SEGF + koff;
          float4 v0 = *(const float4*)gp;
          float4 v1 = *(const float4*)(gp+4);
          float g[8] = {v0.x,v0.y,v0.z,v0.w,v1.x,v1.y,v1.z,v1.w};
          #pragma unroll
          for (int i=0;i<8;i++){
            int f = koff + i;
            y[i] = fmaf(g[i], sc_l[f], sh_l[f]);
          }
        } else {
          #pragma unroll
          for (int i=0;i<8;i++) y[i] = 0.f;
        }
        unsigned int* hp = (unsigned int*)&afh[kk].u;
        unsigned int* lp = (unsigned int*)&afl[kk].u;
        #pragma unroll
        for (int p=0;p<4;p++){
          unsigned short h0 = f2b(y[2*p]),  h1 = f2b(y[2*p+1]);
          unsigned short l0 = f2b(y[2*p] - b2f(h0)), l1 = f2b(y[2*p+1] - b2f(h1));
          hp[p] = (unsigned int)h0 | ((unsigned int)h1 << 16);
          lp[p] = (unsigned int)l0 | ((unsigned int)l1 << 16);
        }
      } else if (seg==1){
        unsigned int* hp = (unsigned int*)&afh[kk].u;
        if (mv){
          uint4 u = *(const uint4*)(A1 + (size_t)m*SEGF + koff);
          float g[8] = {lo2f(u.x),hi2f(u.x),lo2f(u.y),hi2f(u.y),
                        lo2f(u.z),hi2f(u.z),lo2f(u.w),hi2f(u.w)};
          #pragma unroll
          for (int p=0;p<4;p++)
            hp[p] = (unsigned int)f2b(rm*g[2*p]) | ((unsigned int)f2b(rm*g[2*p+1]) << 16);
        } else afh[kk].u = make_uint4(0,0,0,0);
      } else {
        if (mv) afh[kk].u = *(const uint4*)(A2 + (size_t)m*SEGF + koff);
        else    afh[kk].u = make_uint4(0,0,0,0);
      }
    }
    __syncthreads();
    #pragma unroll
    for (int kk=0; kk<2; ++kk){
      #pragma unroll
      for (int t=0;t<4;t++){
        int col = t*16 + mrow;
        int koff = kk*32 + kg*8;
        int byteh = (col*SEGF + koff)*2;          byteh ^= (col & 7) << 4;
        int bytel = ((64 + col)*SEGF + koff)*2;   bytel ^= (col & 7) << 4;
        U16x8 bh, bl;
        bh.u = *(const uint4*)((const char*)wlds + byteh);
        bl.u = *(const uint4*)((const char*)wlds + bytel);
        acc[t] = __builtin_amdgcn_mfma_f32_16x16x32_bf16(afh[kk].s, bh.s, acc[t], 0, 0, 0);
        acc[t] = __builtin_amdgcn_mfma_f32_16x16x32_bf16(afh[kk].s, bl.s, acc[t], 0, 0, 0);
        if (seg==0)
          acc[t] = __builtin_amdgcn_mfma_f32_16x16x32_bf16(afl[kk].s, bh.s, acc[t], 0, 0, 0);
      }
    }
    __syncthreads();
  }

  #pragma unroll
  for (int t=0;t<4;t++){
    int col = t*16 + mrow;
    float bsv = bias[col];
    float s = 0.f, sq = 0.f;
    #pragma unroll
    for (int i=0;i<4;i++){
      int r = brow + kg*4 + i;
      if (r < n){
        float v = fmaxf(acc[t][i] + bsv, 0.f);
        out[(size_t)r*64 + col] = v;
        s += v; sq += v*v;
      }
    }
    s  += __shfl_xor(s, 16);  sq += __shfl_xor(sq, 16);
    s  += __shfl_xor(s, 32);  sq += __shfl_xor(sq, 32);
    if (kg == 0){
      atomicAdd(&ssum[col], s);
      atomicAdd(&ssq[col], sq);
    }
  }
  __syncthreads();
  if (threadIdx.x < 64){
    float* sl = stats + (blockIdx.x & 15)*128;
    atomicAdd(&sl[threadIdx.x], ssum[threadIdx.x]);
    atomicAdd(&sl[64+threadIdx.x], ssq[threadIdx.x]);
  }
}

// ---- BN-scale: reduce stats -> sc/sh; hs = dinv[node]*(sc*g+sh) bf16 ----
__global__ void bn_scale(const float* __restrict__ g_in, const float* __restrict__ dinv,
                         unsigned short* __restrict__ hs,
                         const float* __restrict__ stats, float* __restrict__ scsh,
                         const float* __restrict__ gamma, const float* __restrict__ beta,
                         int n){
  __shared__ float red[128];
  __shared__ float sc[64], sh[64];
  int tid = threadIdx.x;
  if (tid < 128){
    float s = 0.f;
    #pragma unroll
    for (int r=0;r<16;r++) s += stats[r*128 + tid];
    red[tid] = s;
  }
  __syncthreads();
  if (tid < 64){
    float inv_n = 1.f/(float)n;
    float mu = red[tid]*inv_n;
    float var = red[64+tid]*inv_n - mu*mu;
    float a = gamma[tid]*rsqrtf(var + EPS_BN);
    sc[tid] = a;
    sh[tid] = beta[tid] - mu*a;
    if (blockIdx.x == 0){
      scsh[tid] = a;
      scsh[64+tid] = sh[tid];
    }
  }
  __syncthreads();
  int t = blockIdx.x*256 + tid;
  if (t >= n*8) return;
  int fb = (t & 7)*8;
  int node = t >> 3;
  float dv = dinv[node];
  const float* gp = g_in + (size_t)node*64 + fb;
  float4 v0 = *(const float4*)gp;
  float4 v1 = *(const float4*)(gp + 4);
  float vv[8] = {v0.x, v0.y, v0.z, v0.w, v1.x, v1.y, v1.z, v1.w};
  uint4 o;
  unsigned int* op = (unsigned int*)&o;
  #pragma unroll
  for (int p=0;p<4;p++){
    int f0 = fb + 2*p, f1 = f0 + 1;
    float y0 = dv * fmaf(vv[2*p],   sc[f0], sh[f0]);
    float y1 = dv * fmaf(vv[2*p+1], sc[f1], sh[f1]);
    op[p] = (unsigned int)f2b(y0) | ((unsigned int)f2b(y1) << 16);
  }
  ((uint4*)hs)[t] = o;
}

// ---------------- final: BN(layer10) in fp32 + linear 64->2 ----------------
__global__ void final_linear_bn(const float* __restrict__ g_in,
                                const float* __restrict__ stats,
                                const float* __restrict__ gamma, const float* __restrict__ beta,
                                const float* __restrict__ w, const float* __restrict__ b,
                                float* __restrict__ out, int n){
  __shared__ float red[128];
  __shared__ float sc[64], sh[64];
  int tid = threadIdx.x;
  if (tid < 128){
    float s = 0.f;
    #pragma unroll
    for (int r=0;r<16;r++) s += stats[r*128 + tid];
    red[tid] = s;
  }
  __syncthreads();
  if (tid < 64){
    float inv_n = 1.f/(float)n;
    float mu = red[tid]*inv_n;
    float var = red[64+tid]*inv_n - mu*mu;
    float a = gamma[tid]*rsqrtf(var + EPS_BN);
    sc[tid] = a;
    sh[tid] = beta[tid] - mu*a;
  }
  __syncthreads();
  int i = blockIdx.x*256 + tid;
  if (i >= n) return;
  float a0 = b[0], a1 = b[1];
  const float* gp = g_in + (size_t)i*64;
  #pragma unroll
  for (int k=0;k<64;k++){
    float v = fmaf(gp[k], sc[k], sh[k]);
    a0 = fmaf(v, w[k*2+0], a0);
    a1 = fmaf(v, w[k*2+1], a1);
  }
  out[i*2+0] = a0;
  out[i*2+1] = a1;
}

extern "C" void kernel_launch(void* const* d_in, const int* in_sizes, int n_in,
                              void* d_out, int out_size, void* d_ws, size_t ws_size,
                              hipStream_t stream){
  const float* x     = (const float*)d_in[0];
  const int*   ei    = (const int*)d_in[1];
  const float* W1    = (const float*)d_in[2];
  const float* b1    = (const float*)d_in[3];
  const float* Wr    = (const float*)d_in[4];
  const float* br    = (const float*)d_in[5];
  const float* gamma = (const float*)d_in[6];
  const float* beta  = (const float*)d_in[7];
  const float* lw    = (const float*)d_in[8];
  const float* lb    = (const float*)d_in[9];
  const int N = N_NODES, E = N_EDGES;
  const int* row = ei;
  const int* col = ei + E;

  char* ws = (char*)d_ws;
  size_t off = 0;
  auto alloc = [&](size_t bytes)->void*{
    void* p = ws + off; off = (off + bytes + 255) & ~(size_t)255; return p; };
  float*          dinv  = (float*) alloc((size_t)N*4);
  float*          rdeg  = (float*) alloc((size_t)N*4);
  int*            offs  = (int*)   alloc((size_t)(N+1)*4);
  int*            bcnt  = (int*)   alloc(NB*4);
  int*            bbase = (int*)   alloc(NB*4);
  int*            tmp   = (int*)   alloc((size_t)NB*CAP*4);
  int*            ep    = (int*)   alloc((size_t)E*4);
  unsigned short* pb    = (unsigned short*)alloc((size_t)N*64*2);
  unsigned short* qs    = (unsigned short*)alloc((size_t)N*64*2);
  unsigned short* T1s   = (unsigned short*)alloc((size_t)N*64*2);
  unsigned short* Uu    = (unsigned short*)alloc((size_t)N*64*2);
  unsigned short* hs    = (unsigned short*)alloc((size_t)N*64*2);
  float*          gbuf  = (float*) alloc((size_t)N*64*4);
  unsigned short* WTh   = (unsigned short*)alloc((size_t)118784*2);
  unsigned short* WTl   = (unsigned short*)alloc((size_t)118784*2);
  unsigned short* BCT   = (unsigned short*)alloc((size_t)16384*2);
  float*          stats = (float*) alloc((size_t)10*2048*4);
  float*          scsh  = (float*) alloc((size_t)10*128*4);

  hipMemsetAsync(bcnt, 0, NB*4, stream);
  hipMemsetAsync(stats, 0, (size_t)10*2048*4, stream);
  binA<<<(E+4095)/4096, 256, 0, stream>>>(row, col, bcnt, tmp, E);
  scan1024<<<1, NB, 0, stream>>>(bcnt, bbase, offs, N, E);
  binB<<<NB, 256, 0, stream>>>(bcnt, bbase, tmp, offs, dinv, rdeg, ep, N);

  transpose_w<<<(135168+255)/256, 256, 0, stream>>>(W1, Wr, WTh, WTl, BCT);

  int sg = (N+31)/32;
  // ---- layer 1 (reassociated: all spmm in 64-dim) ----
  gemm1_l1<<<(N+63)/64, 256, 0, stream>>>(x, BCT, dinv, pb, qs, N);
  spmm64<2><<<sg, 256, 0, stream>>>(offs, ep, dinv, qs, pb, T1s, N);      // ts
  spmm64<0><<<sg, 256, 0, stream>>>(offs, ep, dinv, T1s, nullptr, Uu, N); // su
  gemm2_l1<<<(N+63)/64, 256, 0, stream>>>(x, WTh, WTl, Uu, b1, gbuf, stats, N);

  // ---- layers 2..10 ----
  for (int L=0; L<9; ++L){
    bn_scale<<<((N*8)+255)/256, 256, 0, stream>>>(gbuf, dinv, hs,
        stats + (size_t)L*2048, scsh + (size_t)L*128,
        gamma + (size_t)L*64, beta + (size_t)L*64, N);
    spmm64<1><<<sg, 256, 0, stream>>>(offs, ep, dinv, hs, nullptr, T1s, N);
    spmm64<0><<<sg, 256, 0, stream>>>(offs, ep, dinv, T1s, nullptr, Uu, N);
    gemm_mfma64<<<(N+63)/64, 256, 0, stream>>>(gbuf, scsh + (size_t)L*128, T1s, Uu, rdeg,
        WTh + 8192 + (size_t)L*12288, WTl + 8192 + (size_t)L*12288,
        br + (size_t)L*64, gbuf, stats + (size_t)(L+1)*2048, N);
  }

  final_linear_bn<<<(N+255)/256, 256, 0, stream>>>(gbuf, stats + (size_t)9*2048,
      gamma + (size_t)9*64, beta + (size_t)9*64, lw, lb, (float*)d_out, N);
}